// Round 3
// baseline (110.458 us; speedup 1.0000x reference)
//
#include <hip/hip_runtime.h>
#include <stdint.h>

// triplet_loss_cl: loss = mean_i(-log(softmax(q G^T)[i,i] + 1e-5)), N=8192, D=256.
// Flash-style, never materialize logits. Fixed offset 64 instead of online max
// (logits bounded; offset cancels exactly in p = exp(l_ii-64)/sum exp(l-64)).
//
// Round 3: k_main has NO LDS and NO barriers. q,g are pre-permuted to bf16
// panel-fragment layout, so B fragments are direct coalesced global b128 loads
// (L2-resident, cs->XCD affinity); compiler interleaves loads with MFMA via
// fine-grained vmcnt — the AITER-style K-loop. q pre-scaled by log2(e) so the
// epilogue is exp2(acc - KOFF) with no fma.

#define LOG2E 1.44269504f
#define KOFF  92.3324826f          // 64 * log2(e); cancels exactly in p = e_ii/Z

typedef __attribute__((ext_vector_type(8))) short short8;  // 8 bf16
typedef __attribute__((ext_vector_type(4))) float f32x4;

__device__ __forceinline__ uint32_t pack2bf(float lo, float hi) {
    return __builtin_amdgcn_perm(__float_as_uint(hi), __float_as_uint(lo), 0x07060302u);
}

// ---- kernel 0: fp32 row-major [8192][256] -> bf16 panel-fragment layout ----
// Panel = 64 rows. Chunk cidx = (ks*4+cf)*64 + quad*16 + l15 holds
// src[64p + cf*16 + l15][ks*32 + quad*8 .. +8). 262144 chunks per array.
// q is pre-scaled by log2(e) so logits come out of MFMA in log2 domain.
__global__ __launch_bounds__(256) void k_cvt(const float* __restrict__ q,
                                             const float* __restrict__ g,
                                             uint4* __restrict__ qb,
                                             uint4* __restrict__ gb) {
    int o = blockIdx.x * 256 + threadIdx.x;        // grid 2048: q then g
    const float* src = q;
    uint4* dst = qb;
    float s = LOG2E;
    if (o >= 262144) { o -= 262144; src = g; dst = gb; s = 1.0f; }
    int p   = o >> 11;
    int b   = (o >> 6) & 31;                       // ks*4 + cf
    int l   = o & 63;
    int row = p * 64 + (b & 3) * 16 + (l & 15);
    int k0  = (b >> 2) * 32 + (l >> 4) * 8;
    const float4* sp = (const float4*)(src + row * 256 + k0);
    float4 a = sp[0], c = sp[1];
    uint4 ov;
    ov.x = pack2bf(a.x * s, a.y * s); ov.y = pack2bf(a.z * s, a.w * s);
    ov.z = pack2bf(c.x * s, c.y * s); ov.w = pack2bf(c.z * s, c.w * s);
    dst[o] = ov;
}

// ---- kernel 1: per-row Z partials (+ diagonal log2-logits), LDS-free ----
// grid 512 = 32 row-tiles (BM=256) x 16 col-splits (512 cols). 4 waves,
// each owns 64 rows (4 rowgroups). B fragments read directly from global.
__global__ __launch_bounds__(256, 2) void k_main(const uint4* __restrict__ qb,
                                                 const uint4* __restrict__ gb,
                                                 float* __restrict__ zpart,
                                                 float* __restrict__ diag) {
    const int tid  = threadIdx.x;
    const int wave = tid >> 6;
    const int lane = tid & 63;
    const int l15  = lane & 15;
    const int quad = lane >> 4;
    const int t    = blockIdx.x >> 4;              // row-tile (256 rows)
    const int cs   = blockIdx.x & 15;              // col-split (512 cols)
    const int rowbase = t * 256 + wave * 64;

    // A fragments: rowgroup rg lives in q-panel (4t+wave) at cf=rg. 128 VGPRs.
    short8 afrag[4][8];
    {
        const char* qp = (const char*)qb + (size_t)(t * 4 + wave) * 32768 + (lane << 4);
#pragma unroll
        for (int rg = 0; rg < 4; ++rg)
#pragma unroll
            for (int ks = 0; ks < 8; ++ks)
                afrag[rg][ks] = *(const short8*)(qp + ((ks * 4 + rg) << 10));
    }

    float zacc[4][4];
#pragma unroll
    for (int rg = 0; rg < 4; ++rg)
#pragma unroll
        for (int r = 0; r < 4; ++r) zacc[rg][r] = 0.f;

    const bool bd = (cs == (t >> 1));              // block's col-slice hits diagonal

    for (int jt = 0; jt < 8; ++jt) {
        const char* gp = (const char*)gb + (size_t)(cs * 8 + jt) * 32768 + (lane << 4);

        f32x4 acc[4][4];                           // [rg][cf]
#pragma unroll
        for (int rg = 0; rg < 4; ++rg)
#pragma unroll
            for (int cf = 0; cf < 4; ++cf) acc[rg][cf] = (f32x4){0.f, 0.f, 0.f, 0.f};

#pragma unroll
        for (int ks = 0; ks < 8; ++ks)
#pragma unroll
            for (int cf = 0; cf < 4; ++cf) {
                short8 b = *(const short8*)(gp + ((ks * 4 + cf) << 10));
#pragma unroll
                for (int rg = 0; rg < 4; ++rg)
                    acc[rg][cf] = __builtin_amdgcn_mfma_f32_16x16x32_bf16(
                        afrag[rg][ks], b, acc[rg][cf], 0, 0, 0);
            }

        // Z += sum exp2(l2 - KOFF). C/D layout: col=lane&15, row=quad*4+reg (m89/m91)
#pragma unroll
        for (int rg = 0; rg < 4; ++rg)
#pragma unroll
            for (int r = 0; r < 4; ++r) {
                float e0 = __builtin_amdgcn_exp2f(acc[rg][0][r] - KOFF);
                float e1 = __builtin_amdgcn_exp2f(acc[rg][1][r] - KOFF);
                float e2 = __builtin_amdgcn_exp2f(acc[rg][2][r] - KOFF);
                float e3 = __builtin_amdgcn_exp2f(acc[rg][3][r] - KOFF);
                zacc[rg][r] += (e0 + e1) + (e2 + e3);
            }

        if (bd && ((jt >> 2) == (t & 1))) {        // tile contains diagonal cols
#pragma unroll
            for (int rg = 0; rg < 4; ++rg)
#pragma unroll
                for (int cf = 0; cf < 4; ++cf)
#pragma unroll
                    for (int r = 0; r < 4; ++r) {
                        int rowg = rowbase + rg * 16 + quad * 4 + r;
                        int colg = (cs << 9) + jt * 64 + cf * 16 + l15;
                        if (rowg == colg) diag[rowg] = acc[rg][cf][r];
                    }
        }
    }

    // fold the 16 column-lane-classes (lanes differing in bits 0..3 share a row)
#pragma unroll
    for (int d = 1; d < 16; d <<= 1)
#pragma unroll
        for (int rg = 0; rg < 4; ++rg)
#pragma unroll
            for (int r = 0; r < 4; ++r)
                zacc[rg][r] += __shfl_xor(zacc[rg][r], d, 64);

    if (l15 == 0) {
#pragma unroll
        for (int rg = 0; rg < 4; ++rg)
#pragma unroll
            for (int r = 0; r < 4; ++r)
                zpart[(rowbase + rg * 16 + quad * 4 + r) * 16 + cs] = zacc[rg][r];
    }
}

// ---- kernel 2a: per-row loss, 32-block tree ----
__global__ __launch_bounds__(256) void k_fin1(const float* __restrict__ zpart,
                                              const float* __restrict__ diag,
                                              float* __restrict__ partial) {
    __shared__ float red[4];
    int r = blockIdx.x * 256 + threadIdx.x;
    const float4* z = (const float4*)(zpart + r * 16);
    float4 a = z[0], b = z[1], c = z[2], d = z[3];
    float Z = (((a.x + a.y) + (a.z + a.w)) + ((b.x + b.y) + (b.z + b.w)))
            + (((c.x + c.y) + (c.z + c.w)) + ((d.x + d.y) + (d.z + d.w)));
    float p = __builtin_amdgcn_exp2f(diag[r] - KOFF) / Z;
    float v = -logf(p + 1e-5f);
#pragma unroll
    for (int dd = 1; dd < 64; dd <<= 1) v += __shfl_xor(v, dd, 64);
    if ((threadIdx.x & 63) == 0) red[threadIdx.x >> 6] = v;
    __syncthreads();
    if (threadIdx.x == 0)
        partial[blockIdx.x] = (red[0] + red[1]) + (red[2] + red[3]);
}

// ---- kernel 2b: final reduce ----
__global__ void k_fin2(const float* __restrict__ partial, float* __restrict__ out) {
    float v = (threadIdx.x < 32) ? partial[threadIdx.x] : 0.f;
#pragma unroll
    for (int d = 1; d < 32; d <<= 1) v += __shfl_xor(v, d, 64);
    if (threadIdx.x == 0) out[0] = v * (1.f / 8192.f);
}

extern "C" void kernel_launch(void* const* d_in, const int* in_sizes, int n_in,
                              void* d_out, int out_size, void* d_ws, size_t ws_size,
                              hipStream_t stream) {
    const float* q = (const float*)d_in[0];
    const float* g = (const float*)d_in[1];
    char* ws = (char*)d_ws;
    uint4* qb     = (uint4*)ws;                                // 4 MiB
    uint4* gb     = (uint4*)(ws + (4u << 20));                 // 4 MiB
    float* diag   = (float*)(ws + (8u << 20));                 // 32 KiB
    float* zpart  = (float*)(ws + (8u << 20) + (32u << 10));   // 512 KiB
    float* partial= (float*)(ws + (8u << 20) + (576u << 10));  // 128 B
    k_cvt <<<2048, 256, 0, stream>>>(q, g, qb, gb);
    k_main<<<512,  256, 0, stream>>>(qb, gb, zpart, diag);
    k_fin1<<<32,   256, 0, stream>>>(zpart, diag, partial);
    k_fin2<<<1,     64, 0, stream>>>(partial, (float*)d_out);
    (void)in_sizes; (void)n_in; (void)out_size; (void)ws_size;
}